// Round 15
// baseline (292.460 us; speedup 1.0000x reference)
//
#include <hip/hip_runtime.h>
#include <stdint.h>
#include <math.h>

typedef __attribute__((ext_vector_type(4))) int i32x4;
typedef __attribute__((ext_vector_type(16))) int i32x16;
typedef __attribute__((ext_vector_type(4))) float f32x4;

constexpr int D_DIM = 1280;   // embedding dim (lin1 K, lin2 N)
constexpr int H_DIM = 5120;   // mlp dim      (lin1 N, lin2 K)

__device__ __forceinline__ void gload_lds16(const void* g, void* l) {
  __builtin_amdgcn_global_load_lds(
      (const __attribute__((address_space(1))) void*)g,
      (__attribute__((address_space(3))) void*)l,
      16, 0, 0);
}

__device__ __forceinline__ i32x4 pack16(const int* __restrict__ p) {
  i32x4 a = *(const i32x4*)(p);
  i32x4 b = *(const i32x4*)(p + 4);
  i32x4 c = *(const i32x4*)(p + 8);
  i32x4 d = *(const i32x4*)(p + 12);
  i32x4 r;
  r.x = (a.x & 255) | ((a.y & 255) << 8) | ((a.z & 255) << 16) | (a.w << 24);
  r.y = (b.x & 255) | ((b.y & 255) << 8) | ((b.z & 255) << 16) | (b.w << 24);
  r.z = (c.x & 255) | ((c.y & 255) << 8) | ((c.z & 255) << 16) | (c.w << 24);
  r.w = (d.x & 255) | ((d.y & 255) << 8) | ((d.z & 255) << 16) | (d.w << 24);
  return r;
}

// ---- fused pack: w1 | w2 | x in ONE launch (int32 sign-extended -> int8) ----
__global__ void __launch_bounds__(256) k_pack3(const int* __restrict__ s1,
                                               const int* __restrict__ s2,
                                               const int* __restrict__ s3,
                                               int8_t* __restrict__ out,
                                               long wn, long nx) {
  long i = ((long)blockIdx.x * 256 + threadIdx.x) * 16;
  if (i >= 2 * wn + nx) return;
  const int* p = (i < wn) ? (s1 + i)
               : (i < 2 * wn) ? (s2 + (i - wn)) : (s3 + (i - 2 * wn));
  *(i32x4*)(out + i) = pack16(p);
}

__global__ void __launch_bounds__(256) k_pack(const int* __restrict__ in,
                                              int8_t* __restrict__ out,
                                              long n) {
  long i = ((long)blockIdx.x * 256 + threadIdx.x) * 16;
  if (i >= n) return;
  *(i32x4*)(out + i) = pack16(in + i);
}

// ---- fused int8 GEMM: 256x128 tile, BK=64, 4 waves (128x64 each), 2 blk/CU --
// D[r][c] = sum_k P[r][k]*S[c][k]; P,S row-major ld=KDIM (NT GEMM).
// BK=64 bank fix: bank = (row&1, slot); swizzle slot ^ ((row>>1)&3) maps 8
// consecutive rows onto all 32 banks (r8's (row&3) aliased rows r and r+4).
// GELU=true  (lin1): P=W1 (r=h), S=x (c=token). sigmoid-GELU + requant ->
//            int8 Q[token][h] (ld ODIM) via pad-260 LDS transpose.
// GELU=false (lin2): P=q (r=token), S=W2 (c=d). fp32 out (ld ODIM), nt stores.
// GROUP_C: group 4 c-tiles (lin1: tokens); else group 4 r-tiles (lin2: tokens).
template <int KDIM, int ODIM, bool GELU, bool GROUP_C>
__global__ void __launch_bounds__(256, 2)
k_gemm(const int8_t* __restrict__ P, const int8_t* __restrict__ S,
       const float* __restrict__ bias, const float* __restrict__ ps1,
       const float* __restrict__ ps2, void* __restrict__ Cout,
       int rtiles, int ctiles) {
  constexpr int BKB = 64;
  constexpr int NT = KDIM / BKB;   // 20 (lin1) / 80 (lin2), both even
  // [P b0 16K][P b1 16K][S b0 8K][S b1 8K] = 48 KB; epilogue reuses [0,33K)
  __shared__ __align__(16) int8_t smem[49152];

  // ---- block mapping: bijective XCD chunk + token-4 grouping (r8) -----------
  const int nwg = rtiles * ctiles;
  int rt, ct;
  {
    const int bid = blockIdx.x;
    const int q = nwg >> 3, r = nwg & 7, x = bid & 7, l = bid >> 3;
    const int swz = (x < r ? x * (q + 1) : r * (q + 1) + (x - r) * q) + l;
    if (GROUP_C && (ctiles & 3) == 0) {
      const int G = rtiles * 4, g = swz / G, rr = swz % G;
      rt = rr >> 2; ct = g * 4 + (rr & 3);
    } else if (!GROUP_C && (rtiles & 3) == 0) {
      const int G = ctiles * 4, g = swz / G, rr = swz % G;
      ct = rr >> 2; rt = g * 4 + (rr & 3);
    } else {
      rt = swz / ctiles; ct = swz % ctiles;
    }
  }

  const int tid = threadIdx.x;
  const int lane = tid & 63, wid = tid >> 6;
  const int wr = wid >> 1, wc = wid & 1;   // 2x2 waves: 128x64 out each
  const int r32 = lane & 31, hi5 = lane >> 5;

  // ---- staging: linear LDS dest, inverse-swizzled global src ----------------
  // dest 16B slot d: row=d>>2, sl=d&3; src in-row slot = sl ^ ((row>>1)&3)
  const int srow = tid >> 2;                              // 0..63
  const int ssl  = (((tid & 3) ^ ((srow >> 1) & 3)) << 4);
  const int8_t* Pth = P + (size_t)(rt * 256 + srow) * KDIM + ssl;
  const int8_t* Sth = S + (size_t)(ct * 128 + srow) * KDIM + ssl;
  const int dT = tid * 16;

  auto STAGE = [&](int buf, int t) {   // P: 4 instr, S: 2 instr per thread
    const int8_t* gp = Pth + t * BKB;
    const int8_t* gs = Sth + t * BKB;
#pragma unroll
    for (int p = 0; p < 4; ++p)
      gload_lds16(gp + (size_t)(p * 64) * KDIM, smem + buf * 16384 + p * 4096 + dT);
#pragma unroll
    for (int p = 0; p < 2; ++p)
      gload_lds16(gs + (size_t)(p * 64) * KDIM,
                  smem + 32768 + buf * 8192 + p * 4096 + dT);
  };

  // ---- fragment offsets: slot = (2ks+hi5) ^ ((r32>>1)&3) --------------------
  // frag rows within P/S differ by multiples of 32 -> (row>>1)&3 == (r32>>1)&3
  const int sw2 = (r32 >> 1) & 3;
  const int ko0 = ((0 + hi5) ^ sw2) << 4;
  const int ko1 = ((2 + hi5) ^ sw2) << 4;
  const int rowP = (wr * 128 + r32) * 64;   // + i*2048 per 32-row P-frag
  const int rowS = (wc * 64 + r32) * 64;    // + j*2048 per 32-row S-frag

  i32x16 acc[4][2] = {};

  auto COMPUTE = [&](int buf) {
    const int8_t* Pb = smem + buf * 16384 + rowP;
    const int8_t* Sb = smem + 32768 + buf * 8192 + rowS;
#pragma unroll
    for (int ks = 0; ks < 2; ++ks) {
      const int ko = ks ? ko1 : ko0;
      i32x4 pf[4], sf[2];
#pragma unroll
      for (int i = 0; i < 4; ++i) pf[i] = *(const i32x4*)(Pb + i * 2048 + ko);
#pragma unroll
      for (int j = 0; j < 2; ++j) sf[j] = *(const i32x4*)(Sb + j * 2048 + ko);
      __builtin_amdgcn_s_setprio(1);
#pragma unroll
      for (int i = 0; i < 4; ++i)
#pragma unroll
        for (int j = 0; j < 2; ++j)
          acc[i][j] =
              __builtin_amdgcn_mfma_i32_32x32x32_i8(pf[i], sf[j], acc[i][j], 0, 0, 0);
      __builtin_amdgcn_s_setprio(0);
    }
  };

  // ---- main loop: r9-verified simple 2-phase dbuf, 1 barrier per tile -------
  STAGE(0, 0);
  __syncthreads();
#pragma unroll 1
  for (int t = 0; t < NT; t += 2) {
    STAGE(1, t + 1);               // NT even: t+1 always valid
    COMPUTE(0);
    __syncthreads();               // buf1 landed; buf0 free
    if (t + 2 < NT) STAGE(0, t + 2);
    COMPUTE(1);
    __syncthreads();
  }

  // ---- epilogue -------------------------------------------------------------
  // 32x32 C/D: col = lane&31, row = (reg&3) + 8*(reg>>2) + 4*(lane>>5)
  const float s1 = *ps1;
  if constexpr (GELU) {
    const float rs = 1.0f / (*ps2);
    int8_t* Q = (int8_t*)Cout;
    // pad-260 transpose tile: 128 tok rows x (256 h + 4 pad) B = 33.3 KB
    // bank(tok, hl) = (tok + (hl>>2)) % 32 -> 32 same-hi5 lanes hit 32 banks
    int8_t* lb = smem;
#pragma unroll
    for (int i = 0; i < 4; ++i) {
#pragma unroll
      for (int qq = 0; qq < 4; ++qq) {
        const int hl = wr * 128 + i * 32 + qq * 8 + hi5 * 4;  // 4 consecutive h
        const f32x4 bv = *(const f32x4*)(bias + rt * 256 + hl);
#pragma unroll
        for (int j = 0; j < 2; ++j) {
          const int tok = wc * 64 + j * 32 + r32;             // local token
          uint32_t pk = 0;
#pragma unroll
          for (int rr = 0; rr < 4; ++rr) {
            const float h = __builtin_fmaf((float)acc[i][j][qq * 4 + rr], s1, bv[rr]);
            // sigmoid-GELU: h * sigma(1.702h); exact in both saturation tails
            const float e = __expf(-1.702f * h);
            const float g = h * __builtin_amdgcn_rcpf(1.0f + e);
            float qf = rintf(g * rs);
            qf = fminf(127.0f, fmaxf(-128.0f, qf));
            pk |= ((uint32_t)((int)qf & 255)) << (rr * 8);
          }
          *(uint32_t*)(lb + tok * 260 + hl) = pk;
        }
      }
    }
    __syncthreads();
    // readback: 4 rows x 256B per instr, coalesced dwordx4 stores (Q stays
    // in L2/L3 for lin2 -- REGULAR stores, r12 lesson)
#pragma unroll
    for (int it = 0; it < 8; ++it) {
      const int row = it * 16 + (tid >> 4);
      const int sl = tid & 15;
      const int8_t* rp = lb + row * 260 + sl * 16;
      i32x4 v;
      v.x = *(const int*)(rp);
      v.y = *(const int*)(rp + 4);
      v.z = *(const int*)(rp + 8);
      v.w = *(const int*)(rp + 12);
      *(i32x4*)(Q + (size_t)(ct * 128 + row) * ODIM + rt * 256 + sl * 16) = v;
    }
  } else {
    float* O = (float*)Cout;
#pragma unroll
    for (int i = 0; i < 4; ++i) {
#pragma unroll
      for (int j = 0; j < 2; ++j) {
        const int col = ct * 128 + wc * 64 + j * 32 + r32;
        const float bv = bias[col];
#pragma unroll
        for (int qq = 0; qq < 4; ++qq)
#pragma unroll
          for (int rr = 0; rr < 4; ++rr) {
            const int row = rt * 256 + wr * 128 + i * 32 + qq * 8 + hi5 * 4 + rr;
            __builtin_nontemporal_store(
                __builtin_fmaf((float)acc[i][j][qq * 4 + rr], s1, bv),
                &O[(size_t)row * ODIM + col]);
          }
      }
    }
  }
}

extern "C" void kernel_launch(void* const* d_in, const int* in_sizes, int n_in,
                              void* d_out, int out_size, void* d_ws, size_t ws_size,
                              hipStream_t stream) {
  (void)in_sizes; (void)n_in; (void)out_size;
  const int*   x32  = (const int*)d_in[0];
  const int*   w132 = (const int*)d_in[1];
  const float* b1   = (const float*)d_in[2];
  const int*   w232 = (const int*)d_in[3];
  const float* b2   = (const float*)d_in[4];
  const float* a1   = (const float*)d_in[5];
  const float* sreq = (const float*)d_in[6];
  const float* a2   = (const float*)d_in[7];
  float* out = (float*)d_out;

  const int M = 4 * 4096;                       // 16384 tokens
  const size_t WN = (size_t)H_DIM * D_DIM;      // 6,553,600 weights each

  int8_t* w1p  = (int8_t*)d_ws;
  int8_t* w2p  = w1p + WN;
  int8_t* base = w2p + WN;

  // chunk M (prefer multiple of 1024 for grouped mappings; min 256)
  size_t avail = ws_size > 2 * WN ? ws_size - 2 * WN : 0;
  size_t rows = avail / (size_t)(D_DIM + H_DIM);
  int Mc = (int)((rows / 1024) * 1024);
  if (Mc < 1024) Mc = (int)((rows / 256) * 256);
  if (Mc < 256) Mc = 256;
  if (Mc > M) Mc = M;

  if (Mc == M) {
    // single chunk: fuse w1+w2+x packing into ONE launch
    const long nx = (long)M * D_DIM;
    const long tot = 2 * (long)WN + nx;
    int8_t* xp = base;
    int8_t* q  = base + (size_t)M * D_DIM;
    k_pack3<<<(int)(tot / 4096), 256, 0, stream>>>(w132, w232, x32, w1p,
                                                   (long)WN, nx);
    // lin1: P = W1 (20 h-tiles of 256), S = x (token tiles)  [arg order!]
    k_gemm<D_DIM, H_DIM, true, true><<<20 * (M / 128), 256, 0, stream>>>(
        w1p, xp, b1, a1, sreq, q, 20, M / 128);
    // lin2: P = q (token tiles of 256), S = W2 (10 d-tiles of 128)
    k_gemm<H_DIM, D_DIM, false, false><<<(M / 256) * 10, 256, 0, stream>>>(
        q, w2p, b2, a2, nullptr, out, M / 256, 10);
    return;
  }

  // fallback: chunked path (small workspace)
  k_pack3<<<(int)(2 * WN / 4096), 256, 0, stream>>>(w132, w232, x32, w1p,
                                                    (long)WN, 0);
  for (int m0 = 0; m0 < M; m0 += Mc) {
    const int mc = (M - m0 < Mc) ? (M - m0) : Mc;
    int8_t* xp = base;
    int8_t* q  = base + (size_t)Mc * D_DIM;
    const size_t nx = (size_t)mc * D_DIM;
    k_pack<<<(int)(nx / 4096), 256, 0, stream>>>(x32 + (size_t)m0 * D_DIM, xp, (long)nx);
    k_gemm<D_DIM, H_DIM, true, true><<<20 * (mc / 128), 256, 0, stream>>>(
        w1p, xp, b1, a1, sreq, q, 20, mc / 128);
    k_gemm<H_DIM, D_DIM, false, false><<<(mc / 256) * 10, 256, 0, stream>>>(
        q, w2p, b2, a2, nullptr, out + (size_t)m0 * D_DIM, mc / 256, 10);
  }
}

// Round 16
// 277.135 us; speedup vs baseline: 1.0553x; 1.0553x over previous
//
#include <hip/hip_runtime.h>
#include <stdint.h>
#include <math.h>

typedef __attribute__((ext_vector_type(4))) int i32x4;
typedef __attribute__((ext_vector_type(16))) int i32x16;
typedef __attribute__((ext_vector_type(4))) float f32x4;

constexpr int D_DIM = 1280;   // embedding dim (lin1 K, lin2 N)
constexpr int H_DIM = 5120;   // mlp dim      (lin1 N, lin2 K)

__device__ __forceinline__ void gload_lds16(const void* g, void* l) {
  __builtin_amdgcn_global_load_lds(
      (const __attribute__((address_space(1))) void*)g,
      (__attribute__((address_space(3))) void*)l,
      16, 0, 0);
}

__device__ __forceinline__ i32x4 pack16(const int* __restrict__ p) {
  i32x4 a = *(const i32x4*)(p);
  i32x4 b = *(const i32x4*)(p + 4);
  i32x4 c = *(const i32x4*)(p + 8);
  i32x4 d = *(const i32x4*)(p + 12);
  i32x4 r;
  r.x = (a.x & 255) | ((a.y & 255) << 8) | ((a.z & 255) << 16) | (a.w << 24);
  r.y = (b.x & 255) | ((b.y & 255) << 8) | ((b.z & 255) << 16) | (b.w << 24);
  r.z = (c.x & 255) | ((c.y & 255) << 8) | ((c.z & 255) << 16) | (c.w << 24);
  r.w = (d.x & 255) | ((d.y & 255) << 8) | ((d.z & 255) << 16) | (d.w << 24);
  return r;
}

// ---- fused pack: w1 | w2 | x in ONE launch (int32 sign-extended -> int8) ----
__global__ void __launch_bounds__(256) k_pack3(const int* __restrict__ s1,
                                               const int* __restrict__ s2,
                                               const int* __restrict__ s3,
                                               int8_t* __restrict__ out,
                                               long wn, long nx) {
  long i = ((long)blockIdx.x * 256 + threadIdx.x) * 16;
  if (i >= 2 * wn + nx) return;
  const int* p = (i < wn) ? (s1 + i)
               : (i < 2 * wn) ? (s2 + (i - wn)) : (s3 + (i - 2 * wn));
  *(i32x4*)(out + i) = pack16(p);
}

__global__ void __launch_bounds__(256) k_pack(const int* __restrict__ in,
                                              int8_t* __restrict__ out,
                                              long n) {
  long i = ((long)blockIdx.x * 256 + threadIdx.x) * 16;
  if (i >= n) return;
  *(i32x4*)(out + i) = pack16(in + i);
}

// ============================================================================
// lin1 kernel (r15-verified): 256x128 tile, BK=64, sigmoid-GELU + requant.
// P=W1 [5120,1280] (r=h), S=x [M,1280] (c=token); Q[token][h] out, ld H_DIM.
// ============================================================================
__global__ void __launch_bounds__(256, 2)
k_lin1(const int8_t* __restrict__ P, const int8_t* __restrict__ S,
       const float* __restrict__ bias, const float* __restrict__ ps1,
       const float* __restrict__ ps2, int8_t* __restrict__ Q, int ctiles) {
  constexpr int KDIM = D_DIM, ODIM = H_DIM;
  constexpr int BKB = 64, NT = KDIM / BKB;   // 20
  constexpr int rtiles = 20;                 // 5120/256 h-tiles
  __shared__ __align__(16) int8_t smem[49152];

  // block mapping: bijective XCD chunk + token-4 grouping
  const int nwg = rtiles * ctiles;
  int rt, ct;
  {
    const int bid = blockIdx.x;
    const int q = nwg >> 3, r = nwg & 7, x = bid & 7, l = bid >> 3;
    const int swz = (x < r ? x * (q + 1) : r * (q + 1) + (x - r) * q) + l;
    if ((ctiles & 3) == 0) {
      const int G = rtiles * 4, g = swz / G, rr = swz % G;
      rt = rr >> 2; ct = g * 4 + (rr & 3);
    } else {
      rt = swz / ctiles; ct = swz % ctiles;
    }
  }

  const int tid = threadIdx.x;
  const int lane = tid & 63, wid = tid >> 6;
  const int wr = wid >> 1, wc = wid & 1;   // 2x2 waves: 128x64 out each
  const int r32 = lane & 31, hi5 = lane >> 5;

  // staging: linear LDS dest, inverse-swizzled src; slot ^ ((row>>1)&3)
  const int srow = tid >> 2;
  const int ssl  = (((tid & 3) ^ ((srow >> 1) & 3)) << 4);
  const int8_t* Pth = P + (size_t)(rt * 256 + srow) * KDIM + ssl;
  const int8_t* Sth = S + (size_t)(ct * 128 + srow) * KDIM + ssl;
  const int dT = tid * 16;

  auto STAGE = [&](int buf, int t) {
    const int8_t* gp = Pth + t * BKB;
    const int8_t* gs = Sth + t * BKB;
#pragma unroll
    for (int p = 0; p < 4; ++p)
      gload_lds16(gp + (size_t)(p * 64) * KDIM, smem + buf * 16384 + p * 4096 + dT);
#pragma unroll
    for (int p = 0; p < 2; ++p)
      gload_lds16(gs + (size_t)(p * 64) * KDIM,
                  smem + 32768 + buf * 8192 + p * 4096 + dT);
  };

  const int sw2 = (r32 >> 1) & 3;
  const int ko0 = ((0 + hi5) ^ sw2) << 4;
  const int ko1 = ((2 + hi5) ^ sw2) << 4;
  const int rowP = (wr * 128 + r32) * 64;
  const int rowS = (wc * 64 + r32) * 64;

  i32x16 acc[4][2] = {};

  auto COMPUTE = [&](int buf) {
    const int8_t* Pb = smem + buf * 16384 + rowP;
    const int8_t* Sb = smem + 32768 + buf * 8192 + rowS;
#pragma unroll
    for (int ks = 0; ks < 2; ++ks) {
      const int ko = ks ? ko1 : ko0;
      i32x4 pf[4], sf[2];
#pragma unroll
      for (int i = 0; i < 4; ++i) pf[i] = *(const i32x4*)(Pb + i * 2048 + ko);
#pragma unroll
      for (int j = 0; j < 2; ++j) sf[j] = *(const i32x4*)(Sb + j * 2048 + ko);
      __builtin_amdgcn_s_setprio(1);
#pragma unroll
      for (int i = 0; i < 4; ++i)
#pragma unroll
        for (int j = 0; j < 2; ++j)
          acc[i][j] =
              __builtin_amdgcn_mfma_i32_32x32x32_i8(pf[i], sf[j], acc[i][j], 0, 0, 0);
      __builtin_amdgcn_s_setprio(0);
    }
  };

  STAGE(0, 0);
  __syncthreads();
#pragma unroll 1
  for (int t = 0; t < NT; t += 2) {
    STAGE(1, t + 1);
    COMPUTE(0);
    __syncthreads();
    if (t + 2 < NT) STAGE(0, t + 2);
    COMPUTE(1);
    __syncthreads();
  }

  // epilogue: sigmoid-GELU + requant -> pad-260 LDS transpose -> dwordx4 st
  const float s1 = *ps1;
  const float rs = 1.0f / (*ps2);
  int8_t* lb = smem;
#pragma unroll
  for (int i = 0; i < 4; ++i) {
#pragma unroll
    for (int qq = 0; qq < 4; ++qq) {
      const int hl = wr * 128 + i * 32 + qq * 8 + hi5 * 4;
      const f32x4 bv = *(const f32x4*)(bias + rt * 256 + hl);
#pragma unroll
      for (int j = 0; j < 2; ++j) {
        const int tok = wc * 64 + j * 32 + r32;
        uint32_t pk = 0;
#pragma unroll
        for (int rr = 0; rr < 4; ++rr) {
          const float h = __builtin_fmaf((float)acc[i][j][qq * 4 + rr], s1, bv[rr]);
          const float e = __expf(-1.702f * h);
          const float g = h * __builtin_amdgcn_rcpf(1.0f + e);
          float qf = rintf(g * rs);
          qf = fminf(127.0f, fmaxf(-128.0f, qf));
          pk |= ((uint32_t)((int)qf & 255)) << (rr * 8);
        }
        *(uint32_t*)(lb + tok * 260 + hl) = pk;
      }
    }
  }
  __syncthreads();
#pragma unroll
  for (int it = 0; it < 8; ++it) {
    const int row = it * 16 + (tid >> 4);
    const int sl = tid & 15;
    const int8_t* rp = lb + row * 260 + sl * 16;
    i32x4 v;
    v.x = *(const int*)(rp);
    v.y = *(const int*)(rp + 4);
    v.z = *(const int*)(rp + 8);
    v.w = *(const int*)(rp + 12);
    *(i32x4*)(Q + (size_t)(ct * 128 + row) * ODIM + rt * 256 + sl * 16) = v;
  }
}

// ============================================================================
// lin2 kernel (r13-verified): 128x128 tile, BK=128, fp32 out (nt stores).
// A=q [M,5120], B=W2 [1280,5120]; out[token][d], ld D_DIM.
// ============================================================================
__global__ void __launch_bounds__(256, 2)
k_lin2(const int8_t* __restrict__ A, const int8_t* __restrict__ B,
       const float* __restrict__ bias, const float* __restrict__ ps1,
       float* __restrict__ Out, int Mtiles) {
  constexpr int KDIM = H_DIM, NDIM = D_DIM;
  constexpr int BM = 128, BN = 128, BKB = 128;
  constexpr int NT = KDIM / BKB;   // 40
  constexpr int BNC = NDIM / BN;   // 10
  constexpr int G = BNC * 4;

  __shared__ __align__(16) int8_t smem[4 * 16384];

  const int nwg = Mtiles * BNC;
  int bm, bn;
  {
    const int bid = blockIdx.x;
    const int q = nwg >> 3, r = nwg & 7, x = bid & 7, l = bid >> 3;
    const int swz = (x < r ? x * (q + 1) : r * (q + 1) + (x - r) * q) + l;
    if ((Mtiles & 3) == 0) {
      const int g = swz / G, rr = swz % G;
      bn = rr >> 2;
      bm = g * 4 + (rr & 3);
    } else {
      bn = swz % BNC;
      bm = swz / BNC;
    }
  }

  const int tid = threadIdx.x;
  const int lane = tid & 63, wid = tid >> 6;
  const int wr = wid >> 1, wc = wid & 1;

  const int srow = tid >> 3;
  const int soff = (((tid & 7) ^ (srow & 7)) << 4);
  const int8_t* Ath = A + (size_t)(bm * BM + srow) * KDIM + soff;
  const int8_t* Bth = B + (size_t)(bn * BN + srow) * KDIM + soff;
  const int dT = tid * 16;

  auto STAGE = [&](int boff, const int8_t* ga, const int8_t* gb) {
#pragma unroll
    for (int p = 0; p < 4; ++p)
      gload_lds16(ga + (size_t)(p * 32) * KDIM, smem + boff + dT + p * 4096);
#pragma unroll
    for (int p = 0; p < 4; ++p)
      gload_lds16(gb + (size_t)(p * 32) * KDIM,
                  smem + 32768 + boff + dT + p * 4096);
  };

  const int r32 = lane & 31, hi5 = lane >> 5;
  const int fsw = (lane & 7) << 4;
  const int kq = hi5 << 4;
  const int8_t* aP[4];
  const int8_t* bP[4];
#pragma unroll
  for (int ks = 0; ks < 4; ++ks) {
    const int koff = (ks * 32 + kq) ^ fsw;
    aP[ks] = smem + (wr * 64 + r32) * BKB + koff;
    bP[ks] = smem + 32768 + (wc * 64 + r32) * BKB + koff;
  }

  i32x16 acc[2][2] = {};

  auto COMPUTE = [&](int boff) {
#pragma unroll
    for (int ks = 0; ks < 4; ++ks) {
      i32x4 a0 = *(const i32x4*)(aP[ks] + boff);
      i32x4 a1 = *(const i32x4*)(aP[ks] + boff + 4096);
      i32x4 b0 = *(const i32x4*)(bP[ks] + boff);
      i32x4 b1 = *(const i32x4*)(bP[ks] + boff + 4096);
      __builtin_amdgcn_s_setprio(1);
      acc[0][0] = __builtin_amdgcn_mfma_i32_32x32x32_i8(a0, b0, acc[0][0], 0, 0, 0);
      acc[0][1] = __builtin_amdgcn_mfma_i32_32x32x32_i8(a0, b1, acc[0][1], 0, 0, 0);
      acc[1][0] = __builtin_amdgcn_mfma_i32_32x32x32_i8(a1, b0, acc[1][0], 0, 0, 0);
      acc[1][1] = __builtin_amdgcn_mfma_i32_32x32x32_i8(a1, b1, acc[1][1], 0, 0, 0);
      __builtin_amdgcn_s_setprio(0);
    }
  };

  STAGE(0, Ath, Bth);
  __syncthreads();
  const int8_t* gA = Ath + BKB;
  const int8_t* gB = Bth + BKB;
#pragma unroll 1
  for (int t = 0; t < NT; t += 2) {
    STAGE(16384, gA, gB);
    COMPUTE(0);
    __syncthreads();
    if (t + 2 < NT) STAGE(0, gA + BKB, gB + BKB);
    COMPUTE(16384);
    __syncthreads();
    gA += 2 * BKB;
    gB += 2 * BKB;
  }

  const float s1 = *ps1;
  const int colb = bn * BN + wc * 64 + r32;
#pragma unroll
  for (int n = 0; n < 2; ++n) {
    const int col = colb + n * 32;
    const float bv = bias[col];
#pragma unroll
    for (int m = 0; m < 2; ++m) {
      const int rowb = bm * BM + wr * 64 + m * 32 + hi5 * 4;
#pragma unroll
      for (int q = 0; q < 4; ++q)
#pragma unroll
        for (int rr = 0; rr < 4; ++rr) {
          const int row = rowb + q * 8 + rr;
          __builtin_nontemporal_store(
              __builtin_fmaf((float)acc[m][n][q * 4 + rr], s1, bv),
              &Out[(size_t)row * NDIM + col]);
        }
    }
  }
}

extern "C" void kernel_launch(void* const* d_in, const int* in_sizes, int n_in,
                              void* d_out, int out_size, void* d_ws, size_t ws_size,
                              hipStream_t stream) {
  (void)in_sizes; (void)n_in; (void)out_size;
  const int*   x32  = (const int*)d_in[0];
  const int*   w132 = (const int*)d_in[1];
  const float* b1   = (const float*)d_in[2];
  const int*   w232 = (const int*)d_in[3];
  const float* b2   = (const float*)d_in[4];
  const float* a1   = (const float*)d_in[5];
  const float* sreq = (const float*)d_in[6];
  const float* a2   = (const float*)d_in[7];
  float* out = (float*)d_out;

  const int M = 4 * 4096;                       // 16384 tokens
  const size_t WN = (size_t)H_DIM * D_DIM;      // 6,553,600 weights each

  int8_t* w1p  = (int8_t*)d_ws;
  int8_t* w2p  = w1p + WN;
  int8_t* base = w2p + WN;

  // chunk M (prefer multiple of 1024 for grouped mappings; min 256)
  size_t avail = ws_size > 2 * WN ? ws_size - 2 * WN : 0;
  size_t rows = avail / (size_t)(D_DIM + H_DIM);
  int Mc = (int)((rows / 1024) * 1024);
  if (Mc < 1024) Mc = (int)((rows / 256) * 256);
  if (Mc < 256) Mc = 256;
  if (Mc > M) Mc = M;

  if (Mc == M) {
    const long nx = (long)M * D_DIM;
    const long tot = 2 * (long)WN + nx;
    int8_t* xp = base;
    int8_t* q  = base + (size_t)M * D_DIM;
    k_pack3<<<(int)(tot / 4096), 256, 0, stream>>>(w132, w232, x32, w1p,
                                                   (long)WN, nx);
    k_lin1<<<20 * (M / 128), 256, 0, stream>>>(w1p, xp, b1, a1, sreq, q, M / 128);
    k_lin2<<<(M / 128) * (D_DIM / 128), 256, 0, stream>>>(q, w2p, b2, a2, out,
                                                          M / 128);
    return;
  }

  // fallback: chunked path (small workspace)
  k_pack3<<<(int)(2 * WN / 4096), 256, 0, stream>>>(w132, w232, x32, w1p,
                                                    (long)WN, 0);
  for (int m0 = 0; m0 < M; m0 += Mc) {
    const int mc = (M - m0 < Mc) ? (M - m0) : Mc;
    int8_t* xp = base;
    int8_t* q  = base + (size_t)Mc * D_DIM;
    const size_t nx = (size_t)mc * D_DIM;
    k_pack<<<(int)(nx / 4096), 256, 0, stream>>>(x32 + (size_t)m0 * D_DIM, xp, (long)nx);
    k_lin1<<<20 * (mc / 128), 256, 0, stream>>>(w1p, xp, b1, a1, sreq, q, mc / 128);
    k_lin2<<<(mc / 128) * (D_DIM / 128), 256, 0, stream>>>(
        q, w2p, b2, a2, out + (size_t)m0 * D_DIM, mc / 128);
  }
}